// Round 3
// baseline (230.059 us; speedup 1.0000x reference)
//
#include <hip/hip_runtime.h>
#include <hip/hip_bf16.h>

typedef short  short8  __attribute__((ext_vector_type(8)));
typedef short  short4v __attribute__((ext_vector_type(4)));
typedef float  floatx4 __attribute__((ext_vector_type(4)));

#define B_  16
#define T_  24
#define N_  512
#define D_  128
#define Z_  12

// ly row stride: 136*2B = 272B -> 16B-aligned ds_read_b128, 2-way bank
// aliasing only (free per m136).
#define LSTRIDE 136

__device__ __forceinline__ short bf16_bits(float x) {
    __hip_bfloat16 h = __float2bfloat16(x);
    return *reinterpret_cast<short*>(&h);
}

__device__ __forceinline__ short8 cvt8(floatx4 a, floatx4 b) {
    short8 v;
    #pragma unroll
    for (int i = 0; i < 4; ++i) v[i] = bf16_bits(a[i]);
    #pragma unroll
    for (int i = 0; i < 4; ++i) v[4 + i] = bf16_bits(b[i]);
    return v;
}

// Load an 8-element MFMA fragment (element offset `off`) as bf16 bits,
// from either an f32 or a bf16 tensor.
__device__ __forceinline__ short8 load_frag(const void* p, int off, bool fm) {
    if (fm) {
        const float* f = (const float*)p + off;
        floatx4 a = *(const floatx4*)f;
        floatx4 b = *(const floatx4*)(f + 4);
        return cvt8(a, b);
    }
    return *(const short8*)((const short*)p + off);
}

__global__ __launch_bounds__(256, 2) void fused_out_kernel(
    const void* __restrict__ Ht_v,
    const void* __restrict__ Hs_v,
    const void* __restrict__ Hm_v,
    const void* __restrict__ W1_v,   // [128][384] row-major
    const void* __restrict__ b1_v,   // [128]
    const void* __restrict__ W2_v,   // [12][128] row-major
    const void* __restrict__ b2_v,   // [12]
    void* __restrict__ out_v)        // [16][12][512]
{
    __shared__ __attribute__((aligned(16))) short ly[16 * LSTRIDE]; // y (bf16)
    __shared__ float lb1[128];

    // ---- dtype sniff (block-uniform scalar) ----
    bool fm;  // true => tensors are float32
    {
        const unsigned short* p = (const unsigned short*)W1_v;
        int big = 0;
        #pragma unroll
        for (int i = 0; i < 64; ++i) big += (((p[i] >> 7) & 0xFF) >= 134);
        fm = (big > 0);
    }

    const int tid  = threadIdx.x;
    const int lane = tid & 63;
    const int w    = tid >> 6;     // wave id 0..3 -> cols w*32..w*32+31
    const int quad = lane >> 4;    // 0..3
    const int l16  = lane & 15;

    if (tid < 128)
        lb1[tid] = fm ? ((const float*)b1_v)[tid]
                      : __bfloat162float(((const __hip_bfloat16*)b1_v)[tid]);

    const int rowbase = blockIdx.x * 16;       // 512 blocks x 16 rows = 8192
    const int bb  = rowbase >> 9;              // batch
    const int nn0 = rowbase & 511;             // node base
    const int abase = ((bb * T_ + (T_ - 1)) * N_ + (nn0 + l16)) * D_;

    floatx4 acc[2];
    acc[0] = (floatx4){0.f, 0.f, 0.f, 0.f};
    acc[1] = (floatx4){0.f, 0.f, 0.f, 0.f};

    // ---- GEMM1: 16 rows x 128 cols, K=384, no LDS, no barriers ----
    #pragma unroll
    for (int ks = 0; ks < 12; ++ks) {
        const void* H = (ks < 4) ? Ht_v : (ks < 8) ? Hs_v : Hm_v;
        const int ka = (ks & 3) * 32 + quad * 8;        // feature in tensor
        short8 af = load_frag(H, abase + ka, fm);
        #pragma unroll
        for (int t = 0; t < 2; ++t) {
            const int col = w * 32 + t * 16 + l16;      // W1 output feature
            short8 bf = load_frag(W1_v, col * 384 + ks * 32 + quad * 8, fm);
            acc[t] = __builtin_amdgcn_mfma_f32_16x16x32_bf16(af, bf, acc[t], 0, 0, 0);
        }
    }

    // ---- epilogue 1: +b1, LeakyReLU, bf16 into ly ----
    // C/D layout: col = lane&15, row = quad*4 + reg  (m89-verified)
    #pragma unroll
    for (int t = 0; t < 2; ++t) {
        const int col = w * 32 + t * 16 + l16;
        const float bias = lb1[col];
        #pragma unroll
        for (int r = 0; r < 4; ++r) {
            float v = acc[t][r] + bias;
            v = (v > 0.f) ? v : 0.01f * v;
            ly[(quad * 4 + r) * LSTRIDE + col] = bf16_bits(v);
        }
    }

    __syncthreads();   // ly complete before GEMM2

    // ---- GEMM2 on wave 0: y[16x128] @ W2^T[128x16] ----
    if (w == 0) {
        floatx4 acc2 = (floatx4){0.f, 0.f, 0.f, 0.f};
        const int z = l16;                      // output head (cols 12..15 dead)
        #pragma unroll
        for (int ks = 0; ks < 4; ++ks) {
            const int ko = ks * 32 + quad * 8;
            short8 af = *(const short8*)&ly[l16 * LSTRIDE + ko];
            short8 bf = (z < Z_) ? load_frag(W2_v, z * 128 + ko, fm)
                                 : (short8){};
            acc2 = __builtin_amdgcn_mfma_f32_16x16x32_bf16(af, bf, acc2, 0, 0, 0);
        }
        if (z < Z_) {
            const float bias = fm ? ((const float*)b2_v)[z]
                                  : __bfloat162float(((const __hip_bfloat16*)b2_v)[z]);
            // C/D: row = quad*4+r -> n = nn0+quad*4+r (4 consecutive) -> vector store
            const int nbase = (bb * Z_ + z) * N_ + nn0 + quad * 4;
            if (fm) {
                floatx4 o;
                #pragma unroll
                for (int r = 0; r < 4; ++r) o[r] = acc2[r] + bias;
                *(floatx4*)((float*)out_v + nbase) = o;
            } else {
                short4v o;
                #pragma unroll
                for (int r = 0; r < 4; ++r) o[r] = bf16_bits(acc2[r] + bias);
                *(short4v*)((short*)out_v + nbase) = o;
            }
        }
    }
}

extern "C" void kernel_launch(void* const* d_in, const int* in_sizes, int n_in,
                              void* d_out, int out_size, void* d_ws, size_t ws_size,
                              hipStream_t stream) {
    (void)in_sizes; (void)n_in; (void)d_ws; (void)ws_size; (void)out_size;
    fused_out_kernel<<<512, 256, 0, stream>>>(
        d_in[0], d_in[1], d_in[2], d_in[3], d_in[4], d_in[5], d_in[6], d_out);
}